// Round 2
// baseline (155.357 us; speedup 1.0000x reference)
//
#include <hip/hip_runtime.h>
#include <hip/hip_bf16.h>
#include <stdint.h>

#define FEATURES 256
#define SYMBOLS  1024
#define NPIX     65536        // 16*64*64
#define M_TILE   64
#define THREADS  256          // 4 waves: wm = wave>>1 (32-row band), wn = wave&1 (64-col half)
#define TILE_BYTES 16384      // B tile: 128 syms x 128 feats fp8, pre-swizzled DMA image
#define EXTRA_BYTES 1024      // mslot[128] + codes[64] + sspart[4]
#define SMEM_BYTES (2 * TILE_BYTES + EXTRA_BYTES)   // 33 KB -> 4 blocks/CU (staggered phases)

typedef float f32x4  __attribute__((ext_vector_type(4)));
typedef float f32x16 __attribute__((ext_vector_type(16)));

// async global->LDS DMA, 16 B per lane; LDS dest = uniform base + lane*16
__device__ __forceinline__ void gld_lds16(const void* g, void* l) {
    __builtin_amdgcn_global_load_lds(
        (const __attribute__((address_space(1))) unsigned int*)g,
        (__attribute__((address_space(3))) unsigned int*)l, 16, 0, 0);
}

// pack 4 fp32 -> 4 fp8 e4m3 (OCP), byte j = element j   [validated R4: absmax 1.95e-3]
__device__ __forceinline__ uint32_t pack_fp8x4(float a, float b, float c, float d) {
    uint32_t u = 0;
    u = __builtin_amdgcn_cvt_pk_fp8_f32(a, b, u, false);
    u = __builtin_amdgcn_cvt_pk_fp8_f32(c, d, u, true);
    return u;
}

// ---- prep: fp8 DMA-image codebook (x256 scale keeps e4m3 normal), wnorm+1 bias, dev=0 ----
// wnorm stores 1.0 + ||w||^2 so main-kernel scores are strictly positive: float bits are
// then directly monotone as uint (no sign-flip in the epilogue). Deviation un-biases by
// subtracting 1.0 per pixel.
// Tile tt=nc*2+kt: syms [nc*128,+128) x feats [kt*128,+128). Row n = 128 B = 16 8-B
// units; unit u (feats kt*128 + (u>>1)*16 + (u&1)*8 ..+8) stored at phys u^(n&15).
__global__ __launch_bounds__(64) void vq_prep(const float* __restrict__ W,
                                              char* __restrict__ Wt,
                                              float* __restrict__ wnorm,
                                              float* __restrict__ devslot) {
    int s = blockIdx.x;
    int lane = threadIdx.x;
    int n  = s & 127;
    int nc = s >> 7;
    f32x4 v = ((const f32x4*)(W + (size_t)s * FEATURES))[lane];
    float ss = v[0]*v[0] + v[1]*v[1] + v[2]*v[2] + v[3]*v[3];
    #pragma unroll
    for (int off = 32; off > 0; off >>= 1) ss += __shfl_xor(ss, off);
    if (lane == 0) wnorm[s] = ss + 1.0f;          // +1 bias: keys strictly positive
    if (s == 0 && lane == 0) *devslot = 0.f;

    if (lane < 32) {
        int kt = lane >> 4;          // 0..1
        int u  = lane & 15;          // 8-B unit within the 128-B tile row
        const float* src = W + (size_t)s * FEATURES + kt * 128 + (u >> 1) * 16 + (u & 1) * 8;
        uint32_t a = pack_fp8x4(256.f*src[0], 256.f*src[1], 256.f*src[2], 256.f*src[3]);
        uint32_t b = pack_fp8x4(256.f*src[4], 256.f*src[5], 256.f*src[6], 256.f*src[7]);
        uint2 w2 = {a, b};
        *(uint2*)(Wt + (size_t)(nc * 2 + kt) * TILE_BYTES + n * 128 + ((u ^ (n & 15)) * 8)) = w2;
    }
}

// ---- main: 32x32x16 fp8, A direct-from-global (no LDS round trip), DMA B, fused argmin ----
__global__ __launch_bounds__(THREADS)
__attribute__((amdgpu_waves_per_eu(4, 4)))   // reg budget 128; 4 blocks/CU -> 4 waves/EU
void vq_main(
        const float*  __restrict__ x,
        const float*  __restrict__ W,
        const char*   __restrict__ Wt,
        const float*  __restrict__ wnorm,
        float*        __restrict__ out,
        float*        __restrict__ devslot) {
    extern __shared__ char smem[];
    const int t    = threadIdx.x;
    const int lane = t & 63;
    const int wave = t >> 6;             // 0..3
    const int l32  = lane & 31;
    const int half = lane >> 5;          // k-half within a 16-K step
    const int wm   = wave >> 1;          // 0..1: 32-pixel-row band
    const int wn   = wave & 1;           // 0..1: 64-symbol-col half
    const int m0   = blockIdx.x * M_TILE;
    const float scale = 1.25f / ((float)NPIX * (float)FEATURES);

    char* const bs0 = smem;
    char* const bs1 = smem + TILE_BYTES;
    uint32_t* mslot = (uint32_t*)(smem + 2 * TILE_BYTES);        // [2][64]
    int*      codes = (int*)(smem + 2 * TILE_BYTES + 512);       // [64]
    float*    sspart = (float*)(smem + 2 * TILE_BYTES + 768);    // [4]

    auto prefetch = [&](int tt) {        // lane-linear: tile tt is contiguous 16 KB
        const char* g = Wt + (size_t)tt * TILE_BYTES;
        char* buf = (tt & 1) ? bs1 : bs0;
        #pragma unroll
        for (int j = 0; j < 4; ++j) {
            int i = wave * 4 + j;        // 16 instrs x 1 KB across 4 waves
            gld_lds16(g + i * 1024 + lane * 16, buf + i * 1024);
        }
    };

    prefetch(0);                         // both initial tiles fly under the A loads
    prefetch(1);

    // ---- A direct from global: af[s] = fp8 of x[row][s*16 + half*8 .. +8), row = l&31 band ----
    // One base pointer per lane; all 32 dwordx4 loads use immediate offsets (s*64, +16 B).
    // wn-twin waves re-read the same rows -> L1/L2 hit, no extra HBM.
    const float* xrow = x + (size_t)(m0 + wm * 32 + l32) * FEATURES + half * 8;
    long af[16];
    float ss = 0.f;
    #pragma unroll
    for (int gblk = 0; gblk < 2; ++gblk) {   // 2 batches of 8 k-steps: 64 VGPRs in flight
        f32x4 xa[8], xb[8];
        #pragma unroll
        for (int j = 0; j < 8; ++j) {
            int s = gblk * 8 + j;
            xa[j] = *(const f32x4*)(xrow + s * 16);
            xb[j] = *(const f32x4*)(xrow + s * 16 + 4);
        }
        #pragma unroll
        for (int j = 0; j < 8; ++j) {
            int s = gblk * 8 + j;
            f32x4 a = xa[j], b = xb[j];
            ss += a[0]*a[0] + a[1]*a[1] + a[2]*a[2] + a[3]*a[3]
                + b[0]*b[0] + b[1]*b[1] + b[2]*b[2] + b[3]*b[3];
            uint32_t lo = pack_fp8x4(a[0], a[1], a[2], a[3]);
            uint32_t hi = pack_fp8x4(b[0], b[1], b[2], b[3]);
            af[s] = (long)(((uint64_t)hi << 32) | (uint64_t)lo);
        }
    }
    #pragma unroll
    for (int off = 32; off > 0; off >>= 1) ss += __shfl_xor(ss, off);
    if (lane == 0) sspart[wave] = ss;    // wn-twins duplicate; only wn==0 summed later

    uint32_t best[16];
    #pragma unroll
    for (int j = 0; j < 16; ++j) best[j] = 0xFFFFFFFFu;

    const int n0 = wn * 64 + l32;        // tile-local B rows for this lane
    const int n1 = wn * 64 + 32 + l32;

    __syncthreads();                     // DMA(0) and DMA(1) drained; sspart visible

    #pragma unroll 1
    for (int nc = 0; nc < 8; ++nc) {
        // wnorm loads issued at iteration top: L2 latency hides under the 32 MFMAs below
        int nb0 = nc * 128 + wn * 64 + l32;
        float w0 = wnorm[nb0], w1 = wnorm[nb0 + 32];
        f32x16 acc0 = {}, acc1 = {};
        #pragma unroll
        for (int kt = 0; kt < 2; ++kt) {
            const int tt = nc * 2 + kt;
            const char* buf = (tt & 1) ? bs1 : bs0;
            #pragma unroll
            for (int s2 = 0; s2 < 8; ++s2) {
                int u = s2 * 2 + half;
                long b0 = *(const long*)(buf + n0 * 128 + ((u ^ (n0 & 15)) * 8));
                long b1 = *(const long*)(buf + n1 * 128 + ((u ^ (n1 & 15)) * 8));
                acc0 = __builtin_amdgcn_mfma_f32_32x32x16_fp8_fp8(af[kt*8+s2], b0, acc0, 0, 0, 0);
                acc1 = __builtin_amdgcn_mfma_f32_32x32x16_fp8_fp8(af[kt*8+s2], b1, acc1, 0, 0, 0);
            }
            if (tt < 15) {
                __syncthreads();                 // readers done + prefetch(tt+1) drained
                if (tt + 2 <= 15) prefetch(tt + 2);
            }
        }
        // epilogue: score = (1 + wnorm) - (2/256)*acc > 0 -> float bits monotone as uint
        #pragma unroll
        for (int r = 0; r < 16; ++r) {
            float v0 = __builtin_fmaf(-0.0078125f, acc0[r], w0);
            float v1 = __builtin_fmaf(-0.0078125f, acc1[r], w1);
            uint32_t k0 = (__float_as_uint(v0) & 0xFFFFFC00u) | (uint32_t)nb0;
            uint32_t k1 = (__float_as_uint(v1) & 0xFFFFFC00u) | (uint32_t)(nb0 + 32);
            uint32_t m  = k0 < k1 ? k0 : k1;
            best[r] = best[r] < m ? best[r] : m;
        }
    }

    // cross-lane merge within each 32-lane group (cols of this lane's rows)
    #pragma unroll
    for (int r = 0; r < 16; ++r) {
        uint32_t v = best[r];
        #pragma unroll
        for (int off = 1; off < 32; off <<= 1) {
            uint32_t ov = (uint32_t)__shfl_xor((int)v, off);
            if (ov < v) v = ov;
        }
        best[r] = v;
    }
    if (l32 == 0) {                      // lanes 0 and 32: rows differ by 4*half
        #pragma unroll
        for (int r = 0; r < 16; ++r) {
            int row = wm * 32 + (r & 3) + 8 * (r >> 2) + 4 * half;
            mslot[wn * 64 + row] = best[r];
        }
    }
    __syncthreads();

    if (t < 64) {                        // merge wn halves; deviation partials (one wave)
        uint32_t s0 = mslot[t], s1 = mslot[64 + t];
        uint32_t s = (s1 < s0) ? s1 : s0;
        codes[t] = (int)(s & 1023u);
        float bv = __uint_as_float(s & 0xFFFFFC00u);  // = 1 + wnorm[code] - 2*best_dot (quantized)
        #pragma unroll
        for (int off = 32; off > 0; off >>= 1) bv += __shfl_xor(bv, off);
        if (t == 0) {
            float sst = sspart[0] + sspart[2];        // wn==0 waves only
            atomicAdd(devslot, scale * (bv - 64.0f + sst));  // un-bias: -1 per pixel
        }
    }
    __syncthreads();

    // ---- out = W[code] (exact fp32 gather from the original codebook) ----
    // two 8-deep batches: 8 KB/wave of W reads in flight, stores fire-and-forget
    f32x4* oblk = (f32x4*)(out + (size_t)m0 * FEATURES);
    #pragma unroll
    for (int h = 0; h < 2; ++h) {
        f32x4 g[8];
        #pragma unroll
        for (int j = 0; j < 8; ++j) {
            int idx = (h * 8 + j) * THREADS + t;
            int row = idx >> 6;          // wave-uniform: (h*8+j)*4 + wave
            int code = __builtin_amdgcn_readfirstlane(codes[row]);
            g[j] = ((const f32x4*)(W + (size_t)code * FEATURES))[idx & 63];
        }
        #pragma unroll
        for (int j = 0; j < 8; ++j)
            oblk[(h * 8 + j) * THREADS + t] = g[j];
    }
}

extern "C" void kernel_launch(void* const* d_in, const int* in_sizes, int n_in,
                              void* d_out, int out_size, void* d_ws, size_t ws_size,
                              hipStream_t stream) {
    const float* x = (const float*)d_in[0];
    const float* W = (const float*)d_in[1];
    float* out = (float*)d_out;

    char*  Wt    = (char*)d_ws;                                   // 256 KB fp8 tiles
    float* wnorm = (float*)((char*)d_ws + 16 * TILE_BYTES);       // 4 KB
    float* devslot = out + (size_t)NPIX * FEATURES;               // d_out tail

    hipFuncSetAttribute(reinterpret_cast<const void*>(vq_main),
                        hipFuncAttributeMaxDynamicSharedMemorySize, SMEM_BYTES);

    vq_prep<<<SYMBOLS, 64, 0, stream>>>(W, Wt, wnorm, devslot);
    vq_main<<<NPIX / M_TILE, THREADS, SMEM_BYTES, stream>>>(x, W, Wt, wnorm, out, devslot);
}

// Round 3
// 147.659 us; speedup vs baseline: 1.0521x; 1.0521x over previous
//
#include <hip/hip_runtime.h>
#include <hip/hip_bf16.h>
#include <stdint.h>

#define FEATURES 256
#define SYMBOLS  1024
#define NPIX     65536        // 16*64*64
#define M_TILE   128
#define THREADS  512          // 8 waves: wm = wave>>1 (32-row band), wn = wave&1 (64-col half)
#define A_BYTES  32768        // A image: 128 rows x 256 B fp8, swizzled, persistent
#define TILE_BYTES 16384      // B tile: 128 syms x 128 feats fp8, pre-swizzled DMA image
#define EXTRA_BYTES 2048      // mslot[256] + codes[128] + sspart[8]
#define SMEM_BYTES (A_BYTES + 2 * TILE_BYTES + EXTRA_BYTES)   // 66.5 KB -> 2 blocks/CU

typedef float f32x4  __attribute__((ext_vector_type(4)));
typedef float f32x16 __attribute__((ext_vector_type(16)));

// async global->LDS DMA, 16 B per lane; LDS dest = uniform base + lane*16
__device__ __forceinline__ void gld_lds16(const void* g, void* l) {
    __builtin_amdgcn_global_load_lds(
        (const __attribute__((address_space(1))) unsigned int*)g,
        (__attribute__((address_space(3))) unsigned int*)l, 16, 0, 0);
}

// pack 4 fp32 -> 4 fp8 e4m3 (OCP), byte j = element j   [validated R4: absmax 1.95e-3]
__device__ __forceinline__ uint32_t pack_fp8x4(float a, float b, float c, float d) {
    uint32_t u = 0;
    u = __builtin_amdgcn_cvt_pk_fp8_f32(a, b, u, false);
    u = __builtin_amdgcn_cvt_pk_fp8_f32(c, d, u, true);
    return u;
}

// ---- prep: fp8 DMA-image codebook (x256 scale keeps e4m3 normal), wnorm+1 bias, dev=0 ----
// wnorm stores 1.0 + ||w||^2 so main-kernel scores are strictly positive: float bits are
// then directly monotone as uint (no sign-flip in the epilogue). Deviation un-biases by
// subtracting 1.0 per pixel.
// Tile tt=nc*2+kt: syms [nc*128,+128) x feats [kt*128,+128). Row n = 128 B = 16 8-B
// units; unit u (feats kt*128 + (u>>1)*16 + (u&1)*8 ..+8) stored at phys u^(n&15).
__global__ __launch_bounds__(64) void vq_prep(const float* __restrict__ W,
                                              char* __restrict__ Wt,
                                              float* __restrict__ wnorm,
                                              float* __restrict__ devslot) {
    int s = blockIdx.x;
    int lane = threadIdx.x;
    int n  = s & 127;
    int nc = s >> 7;
    f32x4 v = ((const f32x4*)(W + (size_t)s * FEATURES))[lane];
    float ss = v[0]*v[0] + v[1]*v[1] + v[2]*v[2] + v[3]*v[3];
    #pragma unroll
    for (int off = 32; off > 0; off >>= 1) ss += __shfl_xor(ss, off);
    if (lane == 0) wnorm[s] = ss + 1.0f;          // +1 bias: keys strictly positive
    if (s == 0 && lane == 0) *devslot = 0.f;

    if (lane < 32) {
        int kt = lane >> 4;          // 0..1
        int u  = lane & 15;          // 8-B unit within the 128-B tile row
        const float* src = W + (size_t)s * FEATURES + kt * 128 + (u >> 1) * 16 + (u & 1) * 8;
        uint32_t a = pack_fp8x4(256.f*src[0], 256.f*src[1], 256.f*src[2], 256.f*src[3]);
        uint32_t b = pack_fp8x4(256.f*src[4], 256.f*src[5], 256.f*src[6], 256.f*src[7]);
        uint2 w2 = {a, b};
        *(uint2*)(Wt + (size_t)(nc * 2 + kt) * TILE_BYTES + n * 128 + ((u ^ (n & 15)) * 8)) = w2;
    }
}

// ---- main: 32x32x16 fp8, A-stationary (32 regs), DMA B, batched-LDS K-loop, fused argmin ----
__global__ __launch_bounds__(THREADS)
__attribute__((amdgpu_waves_per_eu(4, 4)))   // pin 4 waves/EU: reg budget 128, 2 blocks/CU
void vq_main(
        const float*  __restrict__ x,
        const float*  __restrict__ W,
        const char*   __restrict__ Wt,
        const float*  __restrict__ wnorm,
        float*        __restrict__ out,
        float*        __restrict__ devslot) {
    extern __shared__ char smem[];
    const int t    = threadIdx.x;
    const int lane = t & 63;
    const int wave = t >> 6;             // 0..7
    const int l32  = lane & 31;
    const int half = lane >> 5;          // k-half within a 16-K step
    const int wm   = wave >> 1;          // 0..3: 32-pixel-row band
    const int wn   = wave & 1;           // 0..1: 64-symbol-col half
    const int m0   = blockIdx.x * M_TILE;
    const float scale = 1.25f / ((float)NPIX * (float)FEATURES);

    char* const bs0 = smem + A_BYTES;
    char* const bs1 = smem + A_BYTES + TILE_BYTES;
    uint32_t* mslot = (uint32_t*)(smem + A_BYTES + 2 * TILE_BYTES);  // [2][128]
    int*      codes = (int*)(smem + A_BYTES + 2 * TILE_BYTES + 1024);
    float*    sspart = (float*)(smem + A_BYTES + 2 * TILE_BYTES + 1536);

    auto prefetch = [&](int tt) {        // lane-linear: tile tt is contiguous 16 KB
        const char* g = Wt + (size_t)tt * TILE_BYTES;
        char* buf = (tt & 1) ? bs1 : bs0;
        #pragma unroll
        for (int j = 0; j < 2; ++j) {
            int i = wave * 2 + j;        // 16 instrs x 1 KB
            gld_lds16(g + i * 1024 + lane * 16, buf + i * 1024);
        }
    };

    prefetch(0);                         // flies under the stage-A global loads

    // ---- Stage A: x fp32 -> fp8 image; row r = 256 B = 32 8-B units, phys = u^(r&31) ----
    // All 16 f32x4 loads issued up front: 16 KB/wave in flight hides HBM latency.
    const f32x4* xblk = (const f32x4*)(x + (size_t)m0 * FEATURES);
    f32x4 xv[16];
    #pragma unroll
    for (int i = 0; i < 16; ++i) xv[i] = xblk[i * THREADS + t];
    float ss = 0.f;
    #pragma unroll
    for (int i = 0; i < 16; ++i) {
        int idx = i * THREADS + t;       // 8192 float4
        int row = idx >> 6;              // wave-uniform
        int k4  = idx & 63;
        f32x4 v = xv[i];
        ss += v[0]*v[0] + v[1]*v[1] + v[2]*v[2] + v[3]*v[3];
        uint32_t pk = pack_fp8x4(v[0], v[1], v[2], v[3]);
        int u = k4 >> 1;                 // unit 0..31
        *(uint32_t*)(smem + row * 256 + ((u ^ (row & 31)) * 8) + (k4 & 1) * 4) = pk;
    }
    #pragma unroll
    for (int off = 32; off > 0; off >>= 1) ss += __shfl_xor(ss, off);
    if (lane == 0) sspart[wave] = ss;
    __syncthreads();                     // A visible; DMA(0) drained

    // ---- A-stationary: af[s] = 8 fp8 for kstep s (k = s*16 + half*8 ..+8), 32 regs ----
    long af[16];
    {
        int r = wm * 32 + l32;           // pixel row (r&31 == l32)
        #pragma unroll
        for (int s = 0; s < 16; ++s)
            af[s] = *(const long*)(smem + r * 256 + (((s * 2 + half) ^ l32) * 8));
    }
    prefetch(1);

    uint32_t best[16];
    #pragma unroll
    for (int j = 0; j < 16; ++j) best[j] = 0xFFFFFFFFu;

    const int n0 = wn * 64 + l32;        // tile-local B rows for this lane
    const int n1 = wn * 64 + 32 + l32;

    #pragma unroll 1
    for (int nc = 0; nc < 8; ++nc) {
        // wnorm loads issued at iteration top: L2 latency hides under the 32 MFMAs below
        int nb0 = nc * 128 + wn * 64 + l32;
        float w0 = wnorm[nb0], w1 = wnorm[nb0 + 32];
        f32x16 acc0 = {}, acc1 = {};
        #pragma unroll
        for (int kt = 0; kt < 2; ++kt) {
            const int tt = nc * 2 + kt;
            const char* buf = (tt & 1) ? bs1 : bs0;
            // batched B-fragment loads: 16 ds_read_b64 issued together, ONE lgkmcnt wait,
            // then a 16-MFMA burst (two independent acc chains). Removes the per-s2
            // read->mfma latency stall that serialized the K-loop.
            long bf0[8], bf1[8];
            #pragma unroll
            for (int s2 = 0; s2 < 8; ++s2) {
                int u = s2 * 2 + half;
                bf0[s2] = *(const long*)(buf + n0 * 128 + ((u ^ (n0 & 15)) * 8));
                bf1[s2] = *(const long*)(buf + n1 * 128 + ((u ^ (n1 & 15)) * 8));
            }
            #pragma unroll
            for (int s2 = 0; s2 < 8; ++s2) {
                acc0 = __builtin_amdgcn_mfma_f32_32x32x16_fp8_fp8(af[kt*8+s2], bf0[s2], acc0, 0, 0, 0);
                acc1 = __builtin_amdgcn_mfma_f32_32x32x16_fp8_fp8(af[kt*8+s2], bf1[s2], acc1, 0, 0, 0);
            }
            if (tt < 15) {
                __syncthreads();                 // readers done + prefetch(tt+1) drained
                if (tt + 2 <= 15) prefetch(tt + 2);
            }
        }
        // epilogue: score = (1 + wnorm) - (2/256)*acc > 0 -> float bits monotone as uint
        #pragma unroll
        for (int r = 0; r < 16; ++r) {
            float v0 = __builtin_fmaf(-0.0078125f, acc0[r], w0);
            float v1 = __builtin_fmaf(-0.0078125f, acc1[r], w1);
            uint32_t k0 = (__float_as_uint(v0) & 0xFFFFFC00u) | (uint32_t)nb0;
            uint32_t k1 = (__float_as_uint(v1) & 0xFFFFFC00u) | (uint32_t)(nb0 + 32);
            uint32_t m  = k0 < k1 ? k0 : k1;
            best[r] = best[r] < m ? best[r] : m;
        }
    }

    // cross-lane merge within each 32-lane group (cols of this lane's rows)
    #pragma unroll
    for (int r = 0; r < 16; ++r) {
        uint32_t v = best[r];
        #pragma unroll
        for (int off = 1; off < 32; off <<= 1) {
            uint32_t ov = (uint32_t)__shfl_xor((int)v, off);
            if (ov < v) v = ov;
        }
        best[r] = v;
    }
    if (l32 == 0) {                      // lanes 0 and 32: rows differ by 4*half
        #pragma unroll
        for (int r = 0; r < 16; ++r) {
            int row = wm * 32 + (r & 3) + 8 * (r >> 2) + 4 * half;
            mslot[wn * 128 + row] = best[r];
        }
    }
    __syncthreads();

    if (t < 128) {                       // merge wn halves; deviation partials
        uint32_t s0 = mslot[t], s1 = mslot[128 + t];
        uint32_t s = (s1 < s0) ? s1 : s0;
        codes[t] = (int)(s & 1023u);
        float bv = __uint_as_float(s & 0xFFFFFC00u);  // = 1 + wnorm[code] - 2*best_dot (quantized)
        #pragma unroll
        for (int off = 32; off > 0; off >>= 1) bv += __shfl_xor(bv, off);
        if (lane == 0) atomicAdd(devslot, scale * (bv - 64.0f));  // un-bias: -1 per pixel
        if (t == 0) {
            float sst = 0.f;
            #pragma unroll
            for (int w = 0; w < 8; ++w) sst += sspart[w];
            atomicAdd(devslot, scale * sst);
        }
    }
    __syncthreads();

    // ---- out = W[code] (exact fp32 gather from the original codebook) ----
    // two 8-deep batches: 8 KB/wave of W reads in flight, stores fire-and-forget
    f32x4* oblk = (f32x4*)(out + (size_t)m0 * FEATURES);
    #pragma unroll
    for (int h = 0; h < 2; ++h) {
        f32x4 g[8];
        #pragma unroll
        for (int j = 0; j < 8; ++j) {
            int idx = (h * 8 + j) * THREADS + t;
            int row = idx >> 6;          // wave-uniform
            int code = __builtin_amdgcn_readfirstlane(codes[row]);
            g[j] = ((const f32x4*)(W + (size_t)code * FEATURES))[idx & 63];
        }
        #pragma unroll
        for (int j = 0; j < 8; ++j)
            oblk[(h * 8 + j) * THREADS + t] = g[j];
    }
}

extern "C" void kernel_launch(void* const* d_in, const int* in_sizes, int n_in,
                              void* d_out, int out_size, void* d_ws, size_t ws_size,
                              hipStream_t stream) {
    const float* x = (const float*)d_in[0];
    const float* W = (const float*)d_in[1];
    float* out = (float*)d_out;

    char*  Wt    = (char*)d_ws;                                   // 256 KB fp8 tiles
    float* wnorm = (float*)((char*)d_ws + 16 * TILE_BYTES);       // 4 KB
    float* devslot = out + (size_t)NPIX * FEATURES;               // d_out tail

    hipFuncSetAttribute(reinterpret_cast<const void*>(vq_main),
                        hipFuncAttributeMaxDynamicSharedMemorySize, SMEM_BYTES);

    vq_prep<<<SYMBOLS, 64, 0, stream>>>(W, Wt, wnorm, devslot);
    vq_main<<<NPIX / M_TILE, THREADS, SMEM_BYTES, stream>>>(x, W, Wt, wnorm, out, devslot);
}

// Round 4
// 147.186 us; speedup vs baseline: 1.0555x; 1.0032x over previous
//
#include <hip/hip_runtime.h>
#include <hip/hip_bf16.h>
#include <stdint.h>

#define FEATURES 256
#define SYMBOLS  1024
#define NPIX     65536        // 16*64*64
#define M_TILE   128
#define THREADS  512          // 8 waves: wm = wave>>1 (32-row band), wn = wave&1 (64-col half)
#define A_BYTES  32768        // A image: 128 rows x 256 B fp8 (stage only; becomes B-buffers 2,3)
#define TILE_BYTES 16384      // B tile: 128 syms x 128 feats fp8, pre-swizzled DMA image
#define EXTRA_BYTES 6144      // mslot[256](1KB) + codes[128](512B) + sspart(32B) + wlds[1024](4KB)
#define SMEM_BYTES (A_BYTES + 2 * TILE_BYTES + EXTRA_BYTES)   // 70 KB -> 2 blocks/CU (140<160)

typedef float f32x4  __attribute__((ext_vector_type(4)));
typedef float f32x16 __attribute__((ext_vector_type(16)));

// async global->LDS DMA, 16 B per lane; LDS dest = uniform base + lane*16
__device__ __forceinline__ void gld_lds16(const void* g, void* l) {
    __builtin_amdgcn_global_load_lds(
        (const __attribute__((address_space(1))) unsigned int*)g,
        (__attribute__((address_space(3))) unsigned int*)l, 16, 0, 0);
}

// pack 4 fp32 -> 4 fp8 e4m3 (OCP), byte j = element j   [validated R4: absmax 1.95e-3]
__device__ __forceinline__ uint32_t pack_fp8x4(float a, float b, float c, float d) {
    uint32_t u = 0;
    u = __builtin_amdgcn_cvt_pk_fp8_f32(a, b, u, false);
    u = __builtin_amdgcn_cvt_pk_fp8_f32(c, d, u, true);
    return u;
}

// ---- prep: fp8 DMA-image codebook (x256 scale keeps e4m3 normal), wnorm+1 bias, dev=0 ----
// wnorm stores 1.0 + ||w||^2 so main-kernel scores are strictly positive: float bits are
// then directly monotone as uint. Deviation un-biases by subtracting 1.0 per pixel.
// Tile tt=nc*2+kt: syms [nc*128,+128) x feats [kt*128,+128). Row n = 128 B = 16 8-B
// units; unit u (feats kt*128 + (u>>1)*16 + (u&1)*8 ..+8) stored at phys u^(n&15).
__global__ __launch_bounds__(64) void vq_prep(const float* __restrict__ W,
                                              char* __restrict__ Wt,
                                              float* __restrict__ wnorm,
                                              float* __restrict__ devslot) {
    int s = blockIdx.x;
    int lane = threadIdx.x;
    int n  = s & 127;
    int nc = s >> 7;
    f32x4 v = ((const f32x4*)(W + (size_t)s * FEATURES))[lane];
    float ss = v[0]*v[0] + v[1]*v[1] + v[2]*v[2] + v[3]*v[3];
    #pragma unroll
    for (int off = 32; off > 0; off >>= 1) ss += __shfl_xor(ss, off);
    if (lane == 0) wnorm[s] = ss + 1.0f;          // +1 bias: keys strictly positive
    if (s == 0 && lane == 0) *devslot = 0.f;

    if (lane < 32) {
        int kt = lane >> 4;          // 0..1
        int u  = lane & 15;          // 8-B unit within the 128-B tile row
        const float* src = W + (size_t)s * FEATURES + kt * 128 + (u >> 1) * 16 + (u & 1) * 8;
        uint32_t a = pack_fp8x4(256.f*src[0], 256.f*src[1], 256.f*src[2], 256.f*src[3]);
        uint32_t b = pack_fp8x4(256.f*src[4], 256.f*src[5], 256.f*src[6], 256.f*src[7]);
        uint2 w2 = {a, b};
        *(uint2*)(Wt + (size_t)(nc * 2 + kt) * TILE_BYTES + n * 128 + ((u ^ (n & 15)) * 8)) = w2;
    }
}

// ---- main: 32x32x16 fp8, A-stationary, 4-deep DMA B + counted-vmcnt raw barriers ----
// Buffer map: tile tt lives at smem + ((tt+2)&3)*16K  (tiles 0,1 -> old bs0/bs1 region at
// 32K/48K so they can prefetch during stage; tiles 2,3 -> the dead A-image region).
// Reuse distance 4 tiles, barrier-per-tile => 3-tile safety margin.
// Cross-wave DMA visibility: each wave waits vmcnt(N) for ITS share of tile tt+1 BEFORE
// the barrier; the barrier then publishes (wait-then-barrier, 8-phase-template ordering).
// In-loop vmem ops are ONLY the DMAs (wnorm read from an LDS copy) so vmcnt counts are exact:
// steady state outstanding at the wait = tiles {tt+1,tt+2,tt+3} = 6 instr -> vmcnt(4)
// retires tile tt+1. Tail: 4,2,0.
__global__ __launch_bounds__(THREADS)
__attribute__((amdgpu_waves_per_eu(4, 4)))   // pin 4 waves/EU: reg budget 128, 2 blocks/CU
void vq_main(
        const float*  __restrict__ x,
        const float*  __restrict__ W,
        const char*   __restrict__ Wt,
        const float*  __restrict__ wnorm,
        float*        __restrict__ out,
        float*        __restrict__ devslot) {
    extern __shared__ char smem[];
    const int t    = threadIdx.x;
    const int lane = t & 63;
    const int wave = t >> 6;             // 0..7
    const int l32  = lane & 31;
    const int half = lane >> 5;          // k-half within a 16-K step
    const int wm   = wave >> 1;          // 0..3: 32-pixel-row band
    const int wn   = wave & 1;           // 0..1: 64-symbol-col half
    const int m0   = blockIdx.x * M_TILE;
    const float scale = 1.25f / ((float)NPIX * (float)FEATURES);

    uint32_t* mslot = (uint32_t*)(smem + A_BYTES + 2 * TILE_BYTES);          // [2][128]
    int*      codes = (int*)(smem + A_BYTES + 2 * TILE_BYTES + 1024);        // [128]
    float*    sspart = (float*)(smem + A_BYTES + 2 * TILE_BYTES + 1536);     // [8]
    float*    wlds  = (float*)(smem + A_BYTES + 2 * TILE_BYTES + 2048);      // [1024]

    auto prefetch = [&](int tt) {        // lane-linear: tile tt is contiguous 16 KB
        const char* g = Wt + (size_t)tt * TILE_BYTES;
        char* dst = smem + (((tt + 2) & 3) * TILE_BYTES);
        #pragma unroll
        for (int j = 0; j < 2; ++j) {
            int i = wave * 2 + j;        // 16 instrs x 1 KB
            gld_lds16(g + i * 1024 + lane * 16, dst + i * 1024);
        }
    };

    prefetch(0);                         // flies under the stage-A global loads
    prefetch(1);

    // ---- Stage A: x fp32 -> fp8 image; row r = 256 B = 32 8-B units, phys = u^(r&31) ----
    // All 16 f32x4 loads issued up front: 16 KB/wave in flight hides HBM latency.
    const f32x4* xblk = (const f32x4*)(x + (size_t)m0 * FEATURES);
    f32x4 xv[16];
    #pragma unroll
    for (int i = 0; i < 16; ++i) xv[i] = xblk[i * THREADS + t];
    wlds[t] = wnorm[t];                  // LDS copy of wnorm: keeps the K-loop vmcnt clean
    wlds[t + 512] = wnorm[t + 512];
    float ss = 0.f;
    #pragma unroll
    for (int i = 0; i < 16; ++i) {
        int idx = i * THREADS + t;       // 8192 float4
        int row = idx >> 6;              // wave-uniform
        int k4  = idx & 63;
        f32x4 v = xv[i];
        ss += v[0]*v[0] + v[1]*v[1] + v[2]*v[2] + v[3]*v[3];
        uint32_t pk = pack_fp8x4(v[0], v[1], v[2], v[3]);
        int u = k4 >> 1;                 // unit 0..31
        *(uint32_t*)(smem + row * 256 + ((u ^ (row & 31)) * 8) + (k4 & 1) * 4) = pk;
    }
    #pragma unroll
    for (int off = 32; off > 0; off >>= 1) ss += __shfl_xor(ss, off);
    if (lane == 0) sspart[wave] = ss;
    __syncthreads();                     // A visible; DMA(0),(1) + wnorm/x loads drained

    // ---- A-stationary: af[s] = 8 fp8 for kstep s (k = s*16 + half*8 ..+8), 32 regs ----
    long af[16];
    {
        int r = wm * 32 + l32;           // pixel row (r&31 == l32)
        #pragma unroll
        for (int s = 0; s < 16; ++s)
            af[s] = *(const long*)(smem + r * 256 + (((s * 2 + half) ^ l32) * 8));
    }
    __syncthreads();                     // A-image dead for ALL waves -> region becomes bufs 2,3
    prefetch(2);
    prefetch(3);

    uint32_t best[16];
    #pragma unroll
    for (int j = 0; j < 16; ++j) best[j] = 0xFFFFFFFFu;

    const int n0 = wn * 64 + l32;        // tile-local B rows for this lane
    const int n1 = wn * 64 + 32 + l32;

// one K-tile: interleaved ds_read->MFMA (compiler pipelines), then counted-vmcnt wait for
// tile TT+1 (own share), raw barrier (publish), prefetch TT+4. WN/BAR/PF are literals.
#define TILE_STEP(TT, WN, BAR, PF)                                                        \
    {                                                                                     \
        const int tt_ = (TT);                                                             \
        const char* buf = smem + (((tt_ + 2) & 3) * TILE_BYTES);                          \
        const int kt_ = tt_ & 1;                                                          \
        __builtin_amdgcn_s_setprio(1);                                                    \
        _Pragma("unroll")                                                                 \
        for (int s2 = 0; s2 < 8; ++s2) {                                                  \
            int u = s2 * 2 + half;                                                        \
            long b0 = *(const long*)(buf + n0 * 128 + ((u ^ (n0 & 15)) * 8));             \
            long b1 = *(const long*)(buf + n1 * 128 + ((u ^ (n1 & 15)) * 8));             \
            acc0 = __builtin_amdgcn_mfma_f32_32x32x16_fp8_fp8(af[kt_ * 8 + s2], b0, acc0, 0, 0, 0); \
            acc1 = __builtin_amdgcn_mfma_f32_32x32x16_fp8_fp8(af[kt_ * 8 + s2], b1, acc1, 0, 0, 0); \
        }                                                                                 \
        __builtin_amdgcn_s_setprio(0);                                                    \
        asm volatile("s_waitcnt vmcnt(" #WN ")" ::: "memory");                            \
        if (BAR) __builtin_amdgcn_s_barrier();                                            \
        if (PF) prefetch(tt_ + 4);                                                        \
    }

    auto epi = [&](int nc, const f32x16& acc0, const f32x16& acc1) {
        // score = (1 + wnorm) - (2/256)*acc > 0 -> float bits monotone as uint
        int nb0 = nc * 128 + wn * 64 + l32;
        float w0 = wlds[nb0 & 1023], w1 = wlds[(nb0 + 32) & 1023];
        #pragma unroll
        for (int r = 0; r < 16; ++r) {
            float v0 = __builtin_fmaf(-0.0078125f, acc0[r], w0);
            float v1 = __builtin_fmaf(-0.0078125f, acc1[r], w1);
            uint32_t k0 = (__float_as_uint(v0) & 0xFFFFFC00u) | (uint32_t)nb0;
            uint32_t k1 = (__float_as_uint(v1) & 0xFFFFFC00u) | (uint32_t)(nb0 + 32);
            uint32_t m  = k0 < k1 ? k0 : k1;
            best[r] = best[r] < m ? best[r] : m;
        }
    };

    #pragma unroll 1
    for (int nc = 0; nc < 6; ++nc) {
        f32x16 acc0 = {}, acc1 = {};
        TILE_STEP(nc * 2,     4, 1, 1)
        TILE_STEP(nc * 2 + 1, 4, 1, 1)
        epi(nc, acc0, acc1);
    }
    {   // nc = 6: last prefetch was tile 15 (issued at tt=11); tail waits peel 4,2,0
        f32x16 acc0 = {}, acc1 = {};
        TILE_STEP(12, 4, 1, 0)
        TILE_STEP(13, 2, 1, 0)
        epi(6, acc0, acc1);
    }
    {   // nc = 7
        f32x16 acc0 = {}, acc1 = {};
        TILE_STEP(14, 0, 1, 0)
        TILE_STEP(15, 63, 0, 0)          // vmcnt(63) = no-op; nothing outstanding matters
        epi(7, acc0, acc1);
    }
#undef TILE_STEP

    // cross-lane merge within each 32-lane group (cols of this lane's rows)
    #pragma unroll
    for (int r = 0; r < 16; ++r) {
        uint32_t v = best[r];
        #pragma unroll
        for (int off = 1; off < 32; off <<= 1) {
            uint32_t ov = (uint32_t)__shfl_xor((int)v, off);
            if (ov < v) v = ov;
        }
        best[r] = v;
    }
    if (l32 == 0) {                      // lanes 0 and 32: rows differ by 4*half
        #pragma unroll
        for (int r = 0; r < 16; ++r) {
            int row = wm * 32 + (r & 3) + 8 * (r >> 2) + 4 * half;
            mslot[wn * 128 + row] = best[r];
        }
    }
    __syncthreads();

    if (t < 128) {                       // merge wn halves; deviation partials
        uint32_t s0 = mslot[t], s1 = mslot[128 + t];
        uint32_t s = (s1 < s0) ? s1 : s0;
        codes[t] = (int)(s & 1023u);
        float bv = __uint_as_float(s & 0xFFFFFC00u);  // = 1 + wnorm[code] - 2*best_dot (quantized)
        #pragma unroll
        for (int off = 32; off > 0; off >>= 1) bv += __shfl_xor(bv, off);
        if (lane == 0) atomicAdd(devslot, scale * (bv - 64.0f));  // un-bias: -1 per pixel
        if (t == 0) {
            float sst = 0.f;
            #pragma unroll
            for (int w = 0; w < 8; ++w) sst += sspart[w];
            atomicAdd(devslot, scale * sst);
        }
    }
    __syncthreads();

    // ---- out = W[code] (exact fp32 gather from the original codebook) ----
    // two 8-deep batches: 8 KB/wave of W reads in flight, stores fire-and-forget
    f32x4* oblk = (f32x4*)(out + (size_t)m0 * FEATURES);
    #pragma unroll
    for (int h = 0; h < 2; ++h) {
        f32x4 g[8];
        #pragma unroll
        for (int j = 0; j < 8; ++j) {
            int idx = (h * 8 + j) * THREADS + t;
            int row = idx >> 6;          // wave-uniform
            int code = __builtin_amdgcn_readfirstlane(codes[row]);
            g[j] = ((const f32x4*)(W + (size_t)code * FEATURES))[idx & 63];
        }
        #pragma unroll
        for (int j = 0; j < 8; ++j)
            oblk[(h * 8 + j) * THREADS + t] = g[j];
    }
}

extern "C" void kernel_launch(void* const* d_in, const int* in_sizes, int n_in,
                              void* d_out, int out_size, void* d_ws, size_t ws_size,
                              hipStream_t stream) {
    const float* x = (const float*)d_in[0];
    const float* W = (const float*)d_in[1];
    float* out = (float*)d_out;

    char*  Wt    = (char*)d_ws;                                   // 256 KB fp8 tiles
    float* wnorm = (float*)((char*)d_ws + 16 * TILE_BYTES);       // 4 KB
    float* devslot = out + (size_t)NPIX * FEATURES;               // d_out tail

    hipFuncSetAttribute(reinterpret_cast<const void*>(vq_main),
                        hipFuncAttributeMaxDynamicSharedMemorySize, SMEM_BYTES);

    vq_prep<<<SYMBOLS, 64, 0, stream>>>(W, Wt, wnorm, devslot);
    vq_main<<<NPIX / M_TILE, THREADS, SMEM_BYTES, stream>>>(x, W, Wt, wnorm, out, devslot);
}